// Round 2
// baseline (1304.590 us; speedup 1.0000x reference)
//
#include <hip/hip_runtime.h>
#include <hip/hip_bf16.h>
#include <stdint.h>

typedef __attribute__((ext_vector_type(8))) short bf16x8;
typedef __attribute__((ext_vector_type(4))) float f32x4;
typedef __attribute__((ext_vector_type(2))) float f32x2;
typedef __attribute__((ext_vector_type(4))) short short4v;

#define UNITS 1024
#define BATCH 32
#define SEQ 4096
#define CHUNK 64
#define NCHUNK (SEQ / CHUNK)   // 64
#define PAD 8
#define LDK (UNITS + PAD)      // 1032 shorts/row -> 2064B: 16B-aligned rows, banks spread

static __device__ __forceinline__ float bf2f(unsigned short u) {
    union { unsigned int i; float f; } x; x.i = ((unsigned int)u) << 16; return x.f;
}
static __device__ __forceinline__ unsigned short f2bf(float f) {
    __hip_bfloat16 h = __float2bfloat16(f);   // RNE
    return *reinterpret_cast<unsigned short*>(&h);
}
static __device__ __forceinline__ float fast_tanh(float x) {
    float e = __expf(2.0f * x);               // saturates correctly at +/-inf
    return 1.0f - 2.0f / (e + 1.0f);
}

// K0: U_wT[v][u] = bf16(U_w[u][v]); 32x32 LDS tile transpose
__global__ void k_transpose_cast(const float* __restrict__ Uw,
                                 unsigned short* __restrict__ UwT) {
    __shared__ float tile[32][33];
    const int ti = blockIdx.x, tj = blockIdx.y;
    const int c = threadIdx.x;   // 0..31
    const int r0 = threadIdx.y;  // 0..7
#pragma unroll
    for (int rr = 0; rr < 4; ++rr) {
        int r = r0 + rr * 8;
        tile[r][c] = Uw[(size_t)(ti * 32 + r) * UNITS + tj * 32 + c];
    }
    __syncthreads();
#pragma unroll
    for (int rr = 0; rr < 4; ++rr) {
        int rv = r0 + rr * 8;
        UwT[(size_t)(tj * 32 + rv) * UNITS + ti * 32 + c] = f2bf(tile[c][rv]);
    }
}

// K1: ws_vec[b][v] = s_prev[b]@W_w[:,v] + W_b[v] + U_b[v]  (fp32)
__global__ void k_ws(const float* __restrict__ s_prev, const float* __restrict__ Ww,
                     const float* __restrict__ Wb, const float* __restrict__ Ub,
                     float* __restrict__ ws_vec) {
    const int b = blockIdx.y;
    const int v = blockIdx.x * 256 + threadIdx.x;
    const float* sp = s_prev + (size_t)b * UNITS;
    float acc = 0.f;
#pragma unroll 4
    for (int u = 0; u < UNITS; ++u)
        acc = fmaf(sp[u], Ww[(size_t)u * UNITS + v], acc);
    ws_vec[(size_t)b * UNITS + v] = acc + Wb[v] + Ub[v];
}

// K2: fused  u_h GEMM (bf16 MFMA) + tanh + V-dot -> scores
//     + chunk-local softmax stats + e-weighted partial context (single hidden read)
__launch_bounds__(512, 2)
__global__ void k_score_ctx(const float* __restrict__ hidden,
                            const unsigned short* __restrict__ UwT,
                            const float* __restrict__ ws_vec,
                            const float* __restrict__ Vw,
                            const float* __restrict__ Vb,
                            float* __restrict__ scores,
                            float* __restrict__ mstat,
                            float* __restrict__ lstat,
                            float* __restrict__ ctx_part) {
    __shared__ unsigned short h_lds[CHUNK * LDK];  // 132 KB bf16 copy of the row chunk
    __shared__ float ws_lds[UNITS];
    __shared__ float v_lds[UNITS];
    __shared__ float scpart[8][CHUNK];
    __shared__ float sc_lds[CHUNK];
    __shared__ float esc[CHUNK];

    const int tid = threadIdx.x;
    const int bx  = blockIdx.x;
    const int b     = bx / NCHUNK;
    const int chunk = bx % NCHUNK;
    const int lane = tid & 63;
    const int w    = tid >> 6;       // wave 0..7
    const int l15  = lane & 15;
    const int l4   = lane >> 4;

    for (int i = tid; i < UNITS; i += 512) {
        ws_lds[i] = ws_vec[(size_t)b * UNITS + i];
        v_lds[i]  = Vw[i];
    }
    // stage 64x1024 fp32 -> bf16 LDS (coalesced float4 loads)
    {
        const float* hbase = hidden + ((size_t)b * SEQ + (size_t)chunk * CHUNK) * UNITS;
        const int c4 = (tid & 255) * 4;
        const int rhalf = tid >> 8;
#pragma unroll 4
        for (int i = 0; i < 32; ++i) {
            int r = i * 2 + rhalf;
            f32x4 v = *reinterpret_cast<const f32x4*>(hbase + (size_t)r * UNITS + c4);
            short4v p;
            p.x = (short)f2bf(v.x); p.y = (short)f2bf(v.y);
            p.z = (short)f2bf(v.z); p.w = (short)f2bf(v.w);
            *reinterpret_cast<short4v*>(&h_lds[r * LDK + c4]) = p;
        }
    }
    __syncthreads();

    // GEMM: rows 0..63 (A from LDS) x wave's 128 cols (B from L2), K=1024
    float spart[4][4];
#pragma unroll
    for (int fr = 0; fr < 4; ++fr)
#pragma unroll
        for (int j = 0; j < 4; ++j) spart[fr][j] = 0.f;

    for (int outer = 0; outer < 2; ++outer) {
        const int col0 = outer * 512 + w * 64;
        f32x4 acc[4][4];
#pragma unroll
        for (int fr = 0; fr < 4; ++fr)
#pragma unroll
            for (int fc = 0; fc < 4; ++fc) acc[fr][fc] = (f32x4)(0.f);

        for (int k0 = 0; k0 < UNITS; k0 += 32) {
            bf16x8 af[4], bf[4];
#pragma unroll
            for (int fr = 0; fr < 4; ++fr)
                af[fr] = *reinterpret_cast<const bf16x8*>(
                    &h_lds[(fr * 16 + l15) * LDK + k0 + l4 * 8]);
#pragma unroll
            for (int fc = 0; fc < 4; ++fc)
                bf[fc] = *reinterpret_cast<const bf16x8*>(
                    &UwT[(size_t)(col0 + fc * 16 + l15) * UNITS + k0 + l4 * 8]);
#pragma unroll
            for (int fr = 0; fr < 4; ++fr)
#pragma unroll
                for (int fc = 0; fc < 4; ++fc)
                    acc[fr][fc] = __builtin_amdgcn_mfma_f32_16x16x32_bf16(
                        af[fr], bf[fc], acc[fr][fc], 0, 0, 0);
        }
        // epilogue: tanh(ws + u_h) * V, accumulate per-lane partial row sums
#pragma unroll
        for (int fc = 0; fc < 4; ++fc) {
            const int col = col0 + fc * 16 + l15;
            const float wsv = ws_lds[col];
            const float vv  = v_lds[col];
#pragma unroll
            for (int fr = 0; fr < 4; ++fr)
#pragma unroll
                for (int j = 0; j < 4; ++j) {
                    float t = fast_tanh(wsv + acc[fr][fc][j]);
                    spart[fr][j] = fmaf(t, vv, spart[fr][j]);
                }
        }
    }
    // reduce cols across the 16-lane groups
#pragma unroll
    for (int fr = 0; fr < 4; ++fr)
#pragma unroll
        for (int j = 0; j < 4; ++j) {
            float v = spart[fr][j];
            v += __shfl_xor(v, 1);
            v += __shfl_xor(v, 2);
            v += __shfl_xor(v, 4);
            v += __shfl_xor(v, 8);
            spart[fr][j] = v;
        }
    if (l15 == 0) {
#pragma unroll
        for (int fr = 0; fr < 4; ++fr)
#pragma unroll
            for (int j = 0; j < 4; ++j)
                scpart[w][fr * 16 + l4 * 4 + j] = spart[fr][j];
    }
    __syncthreads();

    if (tid < CHUNK) {
        float sc = Vb[0];
#pragma unroll
        for (int ww = 0; ww < 8; ++ww) sc += scpart[ww][tid];
        scores[(size_t)b * SEQ + chunk * CHUNK + tid] = sc;
        sc_lds[tid] = sc;
    }
    __syncthreads();

    if (tid < 64) {  // wave 0: chunk softmax stats
        float v = sc_lds[tid];
        float m = v;
#pragma unroll
        for (int mk = 1; mk < 64; mk <<= 1) m = fmaxf(m, __shfl_xor(m, mk));
        float e = __expf(v - m);
        esc[tid] = e;
        float l = e;
#pragma unroll
        for (int mk = 1; mk < 64; mk <<= 1) l += __shfl_xor(l, mk);
        if (tid == 0) {
            mstat[b * NCHUNK + chunk] = m;
            lstat[b * NCHUNK + chunk] = l;
        }
    }
    __syncthreads();

    // partial context from the LDS bf16 copy (no 2nd HBM read of hidden)
    {
        const int u0 = tid * 2;
        float a0 = 0.f, a1 = 0.f;
#pragma unroll 8
        for (int s = 0; s < CHUNK; ++s) {
            unsigned int p = *reinterpret_cast<const unsigned int*>(&h_lds[s * LDK + u0]);
            float e = esc[s];
            a0 = fmaf(e, bf2f((unsigned short)(p & 0xffffu)), a0);
            a1 = fmaf(e, bf2f((unsigned short)(p >> 16)), a1);
        }
        f32x2 o; o.x = a0; o.y = a1;
        *reinterpret_cast<f32x2*>(&ctx_part[((size_t)(b * NCHUNK + chunk)) * UNITS + u0]) = o;
    }
}

// K3: global softmax over S per batch -> weights output
__global__ void k_weights(const float* __restrict__ scores, float* __restrict__ out_w) {
    const int b = blockIdx.x;
    const int tid = threadIdx.x;
    __shared__ float red[8];
    float sc[16];
#pragma unroll
    for (int i = 0; i < 16; ++i) sc[i] = scores[(size_t)b * SEQ + tid + i * 256];
    float m = sc[0];
#pragma unroll
    for (int i = 1; i < 16; ++i) m = fmaxf(m, sc[i]);
#pragma unroll
    for (int mk = 1; mk < 64; mk <<= 1) m = fmaxf(m, __shfl_xor(m, mk));
    if ((tid & 63) == 0) red[tid >> 6] = m;
    __syncthreads();
    m = fmaxf(fmaxf(red[0], red[1]), fmaxf(red[2], red[3]));
    __syncthreads();
    float l = 0.f;
#pragma unroll
    for (int i = 0; i < 16; ++i) { sc[i] = __expf(sc[i] - m); l += sc[i]; }
#pragma unroll
    for (int mk = 1; mk < 64; mk <<= 1) l += __shfl_xor(l, mk);
    if ((tid & 63) == 0) red[tid >> 6] = l;
    __syncthreads();
    l = red[0] + red[1] + red[2] + red[3];
    const float inv = 1.0f / l;
#pragma unroll
    for (int i = 0; i < 16; ++i)
        out_w[(size_t)b * SEQ + tid + i * 256] = sc[i] * inv;
}

// K4: combine chunk partials -> context output
__global__ void k_ctx_reduce(const float* __restrict__ mstat, const float* __restrict__ lstat,
                             const float* __restrict__ ctx_part, float* __restrict__ out_ctx) {
    const int b = blockIdx.x;
    const int tid = threadIdx.x;
    __shared__ float m_l[NCHUNK], l_l[NCHUNK], f_l[NCHUNK];
    if (tid < NCHUNK) { m_l[tid] = mstat[b * NCHUNK + tid]; l_l[tid] = lstat[b * NCHUNK + tid]; }
    __syncthreads();
    float M = -1e30f;
#pragma unroll 8
    for (int c = 0; c < NCHUNK; ++c) M = fmaxf(M, m_l[c]);
    __syncthreads();
    if (tid < NCHUNK) f_l[tid] = __expf(m_l[tid] - M);
    __syncthreads();
    float L = 0.f;
#pragma unroll 8
    for (int c = 0; c < NCHUNK; ++c) L += f_l[c] * l_l[c];
    const float inv = 1.0f / L;
    const int u = tid * 4;
    f32x4 acc = (f32x4)(0.f);
    for (int c = 0; c < NCHUNK; ++c) {
        float f = f_l[c];
        f32x4 v = *reinterpret_cast<const f32x4*>(
            &ctx_part[((size_t)(b * NCHUNK + c)) * UNITS + u]);
        acc.x = fmaf(f, v.x, acc.x);
        acc.y = fmaf(f, v.y, acc.y);
        acc.z = fmaf(f, v.z, acc.z);
        acc.w = fmaf(f, v.w, acc.w);
    }
    acc.x *= inv; acc.y *= inv; acc.z *= inv; acc.w *= inv;
    *reinterpret_cast<f32x4*>(&out_ctx[(size_t)b * UNITS + u]) = acc;
}

extern "C" void kernel_launch(void* const* d_in, const int* in_sizes, int n_in,
                              void* d_out, int out_size, void* d_ws, size_t ws_size,
                              hipStream_t stream) {
    const float* s_prev = (const float*)d_in[0];
    const float* hidden = (const float*)d_in[1];
    const float* Ww     = (const float*)d_in[2];
    const float* Wb     = (const float*)d_in[3];
    const float* Uw     = (const float*)d_in[4];
    const float* Ub     = (const float*)d_in[5];
    const float* Vw     = (const float*)d_in[6];
    const float* Vb     = (const float*)d_in[7];

    float* out_ctx = (float*)d_out;                 // [32,1024]
    float* out_w   = (float*)d_out + BATCH * UNITS; // [32,4096]

    char* wsb = (char*)d_ws;
    unsigned short* UwT = (unsigned short*)wsb;                       // 2 MiB bf16
    float* ws_vec = (float*)(wsb + (2u << 20));                       // 128 KiB
    float* scores = (float*)(wsb + (2u << 20) + 131072);              // 512 KiB
    float* mstat  = (float*)(wsb + (2u << 20) + 131072 + 524288);     // 8 KiB
    float* lstat  = mstat + BATCH * NCHUNK;                           // 8 KiB
    float* ctx_part = lstat + BATCH * NCHUNK;                         // 8 MiB

    hipLaunchKernelGGL(k_transpose_cast, dim3(32, 32), dim3(32, 8), 0, stream, Uw, UwT);
    hipLaunchKernelGGL(k_ws, dim3(4, 32), dim3(256), 0, stream, s_prev, Ww, Wb, Ub, ws_vec);
    hipLaunchKernelGGL(k_score_ctx, dim3(BATCH * NCHUNK), dim3(512), 0, stream,
                       hidden, UwT, ws_vec, Vw, Vb, scores, mstat, lstat, ctx_part);
    hipLaunchKernelGGL(k_weights, dim3(BATCH), dim3(256), 0, stream, scores, out_w);
    hipLaunchKernelGGL(k_ctx_reduce, dim3(BATCH), dim3(256), 0, stream,
                       mstat, lstat, ctx_part, out_ctx);
}